// Round 1
// 467.381 us; speedup vs baseline: 1.3988x; 1.3988x over previous
//
#include <hip/hip_runtime.h>
#include <hip/hip_bf16.h>

// LGCN_Encoder via Gram-matrix collapse.
//   G = V^T V (512x512, layer-invariant), c0 = V^T ego0
//   c_{k+1} = G (f_k ⊙ c_k)  [tiny]
//   out = (ego0 + V (w1+w2+w3))/4,  w_k = f_{k-1} ⊙ c_{k-1}
// V streamed twice (gram, expand); bf16 trunc-split MFMA (ah*bh+ah*bl+al*bh).
//
// R1 changes vs 655µs baseline (latency-bound: Mfma 11%, VALU 20%, HBM 21%,
// 7.4M LDS bank-conflict cycles):
//  - gram: fragment-shaped LDS (16B blob per (f,n-blk) at its consumer slot)
//    -> conflict-free ds_write_b128 / ds_read_b128 (old NST=40 stride was
//    8-way conflicted on both sides); c0 jobs stage egoT through same path.
//  - gram: next-K-step global loads issued into registers before a RAW
//    s_barrier (asm; only lgkmcnt(0) drained) so they fly across the MFMA
//    phase — no compiler vmcnt(0)-at-barrier drain (T4-lite, m201 pattern).
//  - expand: staging is wave-private -> barriers removed entirely; LDS
//    double-buffered with counted vmcnt(24/16); read 16-way conflict fixed
//    by XOR-swizzling 16B units via pre-swizzled SOURCE addrs (dest linear);
//    wt frags preloaded before the stage batch (in-order vmcnt discipline).
//  - apply_g: 512 blocks, 4-way K-split + LDS reduce (was 128 blocks,
//    512-long serial per-lane loop).

#define N_USERS 29858
#define N_TOTAL 70839
#define DQ 64
#define FD 512
#define NPAD 71168   // 139*512
#define NC 35        // gram split-K chunks (last ragged)
#define CHUNK 2048

typedef __attribute__((ext_vector_type(8))) short short8;
typedef __attribute__((ext_vector_type(4))) short short4v;
typedef __attribute__((ext_vector_type(4))) float f32x4;
typedef unsigned int u32;
typedef unsigned short u16;

static __device__ __forceinline__ u32 f32u(float x){union{float f;u32 u;}a;a.f=x;return a.u;}
static __device__ __forceinline__ float uf32(u32 u){union{u32 u;float f;}a;a.u=u;return a.f;}
// pack high halves: (hi16(x1)<<16) | hi16(x0)
static __device__ __forceinline__ u32 pack_h(u32 x0, u32 x1){
  return __builtin_amdgcn_perm(x1, x0, 0x07060302u);
}
// exact trunc split of two f32 into bf16 h-pair and l-pair dwords
static __device__ __forceinline__ void split_pair(u32 x0, u32 x1, u32& hp, u32& lp) {
  hp = pack_h(x0, x1);
  u32 l0 = f32u(uf32(x0) - uf32(x0 & 0xFFFF0000u));
  u32 l1 = f32u(uf32(x1) - uf32(x1 & 0xFFFF0000u));
  lp = pack_h(l0, l1);
}
union U8x { u32 u[4]; short8 s; };

static __device__ __forceinline__ u16 bf16_rne(float x) {
  u32 u = f32u(x);
  return (u16)((u + 0x7FFFu + ((u >> 16) & 1u)) >> 16);
}
static __device__ __forceinline__ void split2(float x, u16& h, u16& l) {
  h = bf16_rne(x);
  l = bf16_rne(x - uf32(((u32)h) << 16));
}

static __device__ __forceinline__ void load_lds16(const float* g, float* l) {
  __builtin_amdgcn_global_load_lds(
      (const __attribute__((address_space(1))) u32*)(g),
      (__attribute__((address_space(3))) u32*)(l), 16, 0, 0);
}

// ---------------------------------------------------------------- init
// out = concat(user,item); egoT_h/l[d][n] = split(ego0[n][d]); zero-pad n>=N_TOTAL
__global__ __launch_bounds__(256) void init_kernel(
    const float* __restrict__ u, const float* __restrict__ it,
    float* __restrict__ out, u16* __restrict__ egoT_h, u16* __restrict__ egoT_l) {
  const int n0 = blockIdx.x * 64;
  const int t = threadIdx.x;
  const int nq = t & 15, dq = t >> 4;
  f32x4 rows[4];
#pragma unroll
  for (int r = 0; r < 4; ++r) {
    int n = n0 + nq * 4 + r;
    f32x4 val = {0.f, 0.f, 0.f, 0.f};
    if (n < N_TOTAL) {
      const float* src = (n < N_USERS) ? (u + (size_t)n * DQ)
                                       : (it + (size_t)(n - N_USERS) * DQ);
      val = *(const f32x4*)(src + dq * 4);
      *(f32x4*)(out + (size_t)n * DQ + dq * 4) = val;
    }
    rows[r] = val;
  }
#pragma unroll
  for (int i = 0; i < 4; ++i) {
    int d = dq * 4 + i;
    short4v hv, lv;
#pragma unroll
    for (int r = 0; r < 4; ++r) {
      u16 h, l;
      split2(rows[r][i], h, l);
      hv[r] = (short)h; lv[r] = (short)l;
    }
    *(short4v*)(egoT_h + (size_t)d * NPAD + n0 + nq * 4) = hv;
    *(short4v*)(egoT_l + (size_t)d * NPAD + n0 + nq * 4) = lv;
  }
}

// ---------------------------------------------------------------- gram
// 14 jobs: 0..11 G-tiles (256 rows x 64 cols, upper-incl), 12..13 c0-tiles.
// LDS holds split V-slices as MFMA-fragment-shaped 16B blobs:
//   unit(f, nb) = (f&15) + ((f>>4)&3)*64 + (f>>6)*256 + nb*16   (nb = n>>3)
// so both staging writes and fragment reads are contiguous b128 ops
// (conflict-free). Next K-step's global loads are prefetched into registers
// before a raw s_barrier (no vmcnt drain) and land during the MFMA phase.
__global__ __launch_bounds__(256, 2) void gram_kernel(
    const float* __restrict__ v, const u16* __restrict__ egoT_h,
    const u16* __restrict__ egoT_l, float* __restrict__ parts) {
  __shared__ short8 HAh[1024];   // 256 f x 4 n-blk, 16 KB
  __shared__ short8 HAl[1024];
  __shared__ short8 HBh[256];    // 64 f x 4 n-blk, 4 KB
  __shared__ short8 HBl[256];

  const int job = blockIdx.x;
  const int n0c = blockIdx.y * CHUNK;
  const int nend = min(n0c + CHUNK, NPAD);
  const bool isC0 = (job >= 12);
  const int itile = isC0 ? (job - 12) : (job < 8 ? 0 : 1);
  const int fA = itile * 256;
  const int jcol = isC0 ? 0 : (job < 8 ? job : job - 4);
  const int colbase = jcol * 64;
  const bool reuseB = !isC0 && (colbase >= fA) && (colbase + 64 <= fA + 256);
  const bool stageB = !isC0 && !reuseB;
  const int cb0q = reuseB ? ((colbase - fA) >> 6) : 0;

  const int t = threadIdx.x;
  const int lane = t & 63, wv = t >> 6;
  const int m16 = lane & 15, quad = lane >> 4;
  const int fl = lane, nq = wv;

  f32x4 acc[4][4];
#pragma unroll
  for (int a = 0; a < 4; ++a)
#pragma unroll
    for (int b = 0; b < 4; ++b) acc[a][b] = (f32x4){0.f, 0.f, 0.f, 0.f};

  u32 xA[4][8];
  u32 xB[8];
  short8 xBh, xBl;

  auto issue = [&](int n0) {
#pragma unroll
    for (int seg = 0; seg < 4; ++seg)
#pragma unroll
      for (int r = 0; r < 8; ++r) {
        int n = n0 + nq * 8 + r;
        xA[seg][r] = (n < N_TOTAL) ? f32u(v[(size_t)n * FD + fA + seg * 64 + fl]) : 0u;
      }
    if (stageB) {
#pragma unroll
      for (int r = 0; r < 8; ++r) {
        int n = n0 + nq * 8 + r;
        xB[r] = (n < N_TOTAL) ? f32u(v[(size_t)n * FD + colbase + fl]) : 0u;
      }
    }
    if (isC0) {  // egoT already split: direct fragment copy
      xBh = *(const short8*)(egoT_h + (size_t)fl * NPAD + n0 + nq * 8);
      xBl = *(const short8*)(egoT_l + (size_t)fl * NPAD + n0 + nq * 8);
    }
  };

  issue(n0c);

  for (int n0 = n0c; n0 < nend; n0 += 32) {
    // all waves done reading LDS of previous step (reads consumed by MFMAs)
    asm volatile("s_barrier" ::: "memory");

    const int uw = (fl & 15) + ((fl >> 4) & 3) * 64 + nq * 16;
#pragma unroll
    for (int seg = 0; seg < 4; ++seg) {
      U8x H, L;
#pragma unroll
      for (int p = 0; p < 4; ++p)
        split_pair(xA[seg][2 * p], xA[seg][2 * p + 1], H.u[p], L.u[p]);
      HAh[uw + seg * 256] = H.s;
      HAl[uw + seg * 256] = L.s;
    }
    if (stageB) {
      U8x H, L;
#pragma unroll
      for (int p = 0; p < 4; ++p)
        split_pair(xB[2 * p], xB[2 * p + 1], H.u[p], L.u[p]);
      HBh[uw] = H.s;
      HBl[uw] = L.s;
    } else if (isC0) {
      HBh[uw] = xBh;
      HBl[uw] = xBl;
    }

    // prefetch next step's globals: stay in flight across barrier + MFMAs
    if (n0 + 32 < nend) issue(n0 + 32);

    asm volatile("s_waitcnt lgkmcnt(0)" ::: "memory");  // ds_writes visible
    asm volatile("s_barrier" ::: "memory");             // NOT vmcnt-drained

    short8 ah[4], al[4];
#pragma unroll
    for (int mt = 0; mt < 4; ++mt) {
      int u = m16 + mt * 64 + wv * 256 + quad * 16;
      ah[mt] = HAh[u];
      al[mt] = HAl[u];
    }
#pragma unroll
    for (int ct = 0; ct < 4; ++ct) {
      short8 bh, bl;
      if (reuseB) {
        int u = m16 + ct * 64 + cb0q * 256 + quad * 16;
        bh = HAh[u]; bl = HAl[u];
      } else {
        int u = m16 + ct * 64 + quad * 16;
        bh = HBh[u]; bl = HBl[u];
      }
#pragma unroll
      for (int mt = 0; mt < 4; ++mt) {
        acc[mt][ct] = __builtin_amdgcn_mfma_f32_16x16x32_bf16(ah[mt], bh, acc[mt][ct], 0, 0, 0);
        acc[mt][ct] = __builtin_amdgcn_mfma_f32_16x16x32_bf16(ah[mt], bl, acc[mt][ct], 0, 0, 0);
        acc[mt][ct] = __builtin_amdgcn_mfma_f32_16x16x32_bf16(al[mt], bh, acc[mt][ct], 0, 0, 0);
      }
    }
  }

  float* pb = parts + (size_t)blockIdx.y * (512 * 576);
  const int cb = isC0 ? 512 : colbase;
#pragma unroll
  for (int mt = 0; mt < 4; ++mt) {
    int row = fA + wv * 64 + mt * 16 + quad * 4;
#pragma unroll
    for (int ct = 0; ct < 4; ++ct) {
      int col = cb + ct * 16 + m16;
#pragma unroll
      for (int reg = 0; reg < 4; ++reg)
        pb[(size_t)(row + reg) * 576 + col] = acc[mt][ct][reg];
    }
  }
}

// ---------------------------------------------------------------- finalize
// Sum partials; mirror lower triangle of G; emit G [512][512] and c0 [512][64].
__global__ __launch_bounds__(256) void finalize_kernel(
    const float* __restrict__ parts, float* __restrict__ G, float* __restrict__ c0) {
  int idx = blockIdx.x * 256 + threadIdx.x;  // 512*576
  int r = idx / 576, c = idx % 576;
  float s = 0.f;
  if (c >= 512) {
    for (int p = 0; p < NC; ++p) s += parts[(size_t)p * (512 * 576) + r * 576 + c];
    c0[r * 64 + (c - 512)] = s;
  } else {
    bool direct = (c >> 6) >= 4 * (r >> 8);
    int rr = direct ? r : c, cc = direct ? c : r;
    for (int p = 0; p < NC; ++p) s += parts[(size_t)p * (512 * 576) + rr * 576 + cc];
    G[r * 512 + c] = s;
  }
}

// ---------------------------------------------------------------- apply_g
// cout = G @ (filt ⊙ cin), fp32 VALU. grid 512: one row per block,
// K split 4-ways across waves, LDS reduce.
__global__ __launch_bounds__(256) void apply_g_kernel(
    const float* __restrict__ G, const float* __restrict__ filt,
    const float* __restrict__ cin, float* __restrict__ cout) {
  __shared__ float red[4][64];
  const int t = threadIdx.x;
  const int i = blockIdx.x;
  const int sub = t >> 6, d = t & 63;
  float s = 0.f;
#pragma unroll 8
  for (int j = sub * 128; j < (sub + 1) * 128; ++j)
    s += G[i * 512 + j] * (filt[j] * cin[j * 64 + d]);
  red[sub][d] = s;
  __syncthreads();
  if (sub == 0)
    cout[i * 64 + d] = red[0][d] + red[1][d] + red[2][d] + red[3][d];
}

// ---------------------------------------------------------------- prep_wt
// wsum = f0⊙c0 + f1⊙c1 + f2⊙c2; wt_h/l[d][f] = split(wsum[f][d])
__global__ __launch_bounds__(256) void prep_wt_kernel(
    const float* __restrict__ filters, const float* __restrict__ c0,
    const float* __restrict__ c1, const float* __restrict__ c2,
    u16* __restrict__ wt_h, u16* __restrict__ wt_l) {
  int idx = blockIdx.x * 256 + threadIdx.x;  // 64*512
  int d = idx >> 9, f = idx & 511;
  float w = filters[f] * c0[f * 64 + d] + filters[512 + f] * c1[f * 64 + d] +
            filters[1024 + f] * c2[f * 64 + d];
  u32 xu = f32u(w);
  u32 h = xu & 0xFFFF0000u;
  u32 lu = f32u(w - uf32(h));
  wt_h[d * FD + f] = (u16)(xu >> 16);
  wt_l[d * FD + f] = (u16)(lu >> 16);
}

// ---------------------------------------------------------------- expand
// out = (out + V @ wsum) * 0.25. Wave-private double-buffered gl_lds staging,
// NO barriers (each wave reads only its own rows); counted vmcnt keeps the
// next tile in flight under the MFMAs. 16B units XOR-swizzled by row&7 via
// pre-swizzled SOURCE addresses (LDS dest stays linear) -> 2-way reads.
__global__ __launch_bounds__(256) void expand_kernel(
    const float* __restrict__ v, const u16* __restrict__ wt_h,
    const u16* __restrict__ wt_l, float* __restrict__ out) {
  __shared__ float raw[2][128 * 64];
  const int t = threadIdx.x;
  const int lane = t & 63, wv = t >> 6;
  const int m16 = lane & 15, quad = lane >> 4;
  const int nb = blockIdx.x * 128;

  f32x4 acc[2][4];
#pragma unroll
  for (int a = 0; a < 2; ++a)
#pragma unroll
    for (int b = 0; b < 4; ++b) acc[a][b] = (f32x4){0.f, 0.f, 0.f, 0.f};

  auto stage = [&](int buf, int fs) {
#pragma unroll
    for (int g = 0; g < 8; ++g) {
      int rl = g * 4 + (lane >> 4);            // wave-local row 0..31
      int sw = rl & 7;                         // dest row & 7 (wv*32 ≡ 0 mod 8)
      int grow = min(nb + wv * 32 + rl, N_TOTAL - 1);  // padded rows discarded later
      const float* gp = v + (size_t)grow * FD + fs + (((lane & 15) ^ sw) << 2);
      load_lds16(gp, &raw[buf][(wv * 32 + g * 4) * 64]);
    }
  };

  stage(0, 0);
  for (int it = 0; it < 8; ++it) {
    const int buf = it & 1, fs = it * 64;
    // wt fragments for this iter FIRST (older than next stage batch, so the
    // compiler's wait for them cannot drain the prefetch — vmcnt is in-order)
    short8 pbh[2][4], pbl[2][4];
#pragma unroll
    for (int k = 0; k < 2; ++k)
#pragma unroll
      for (int ct = 0; ct < 4; ++ct) {
        const size_t off = (size_t)(ct * 16 + m16) * FD + fs + k * 32 + quad * 8;
        pbh[k][ct] = *(const short8*)(wt_h + off);
        pbl[k][ct] = *(const short8*)(wt_l + off);
      }
    asm volatile("" ::: "memory");  // pin wt loads before stage batch
    if (it + 1 < 8) {
      stage(buf ^ 1, fs + 64);
      // outstanding: cur stage (<=8, oldest) + 16 wt + 8 next = drain cur only
      asm volatile("s_waitcnt vmcnt(24)" ::: "memory");
    } else {
      asm volatile("s_waitcnt vmcnt(16)" ::: "memory");
    }
#pragma unroll
    for (int k0i = 0; k0i < 2; ++k0i) {
      short8 ah[2], al[2];
#pragma unroll
      for (int mt = 0; mt < 2; ++mt) {
        const float* rb = &raw[buf][(wv * 32 + mt * 16 + m16) * 64];
        const int sw = m16 & 7;                // row & 7
        const int j0 = k0i * 8 + quad * 2;     // 16B-unit index
        f32x4 xa = *(const f32x4*)(rb + ((j0 ^ sw) << 2));
        f32x4 xb = *(const f32x4*)(rb + (((j0 + 1) ^ sw) << 2));
        U8x H, L;
        split_pair(f32u(xa[0]), f32u(xa[1]), H.u[0], L.u[0]);
        split_pair(f32u(xa[2]), f32u(xa[3]), H.u[1], L.u[1]);
        split_pair(f32u(xb[0]), f32u(xb[1]), H.u[2], L.u[2]);
        split_pair(f32u(xb[2]), f32u(xb[3]), H.u[3], L.u[3]);
        ah[mt] = H.s; al[mt] = L.s;
      }
#pragma unroll
      for (int ct = 0; ct < 4; ++ct) {
#pragma unroll
        for (int mt = 0; mt < 2; ++mt) {
          acc[mt][ct] = __builtin_amdgcn_mfma_f32_16x16x32_bf16(ah[mt], pbh[k0i][ct], acc[mt][ct], 0, 0, 0);
          acc[mt][ct] = __builtin_amdgcn_mfma_f32_16x16x32_bf16(ah[mt], pbl[k0i][ct], acc[mt][ct], 0, 0, 0);
          acc[mt][ct] = __builtin_amdgcn_mfma_f32_16x16x32_bf16(al[mt], pbh[k0i][ct], acc[mt][ct], 0, 0, 0);
        }
      }
    }
  }

#pragma unroll
  for (int mt = 0; mt < 2; ++mt) {
    int nrow = nb + wv * 32 + mt * 16 + quad * 4;
#pragma unroll
    for (int ct = 0; ct < 4; ++ct) {
      int d = ct * 16 + m16;
#pragma unroll
      for (int reg = 0; reg < 4; ++reg) {
        int n = nrow + reg;
        if (n < N_TOTAL) {
          float* op = out + (size_t)n * DQ + d;
          *op = (*op + acc[mt][ct][reg]) * 0.25f;
        }
      }
    }
  }
}

// ---------------------------------------------------------------- launch
extern "C" void kernel_launch(void* const* d_in, const int* in_sizes, int n_in,
                              void* d_out, int out_size, void* d_ws, size_t ws_size,
                              hipStream_t stream) {
  const float* user_emb = (const float*)d_in[0];
  const float* item_emb = (const float*)d_in[1];
  const float* v        = (const float*)d_in[2];
  const float* filters  = (const float*)d_in[3];
  float* out = (float*)d_out;

  u16* egoT_h = (u16*)d_ws;                                   // 64*NPAD
  u16* egoT_l = egoT_h + (size_t)DQ * NPAD;                   // 64*NPAD
  float* parts = (float*)(egoT_l + (size_t)DQ * NPAD);        // NC*512*576
  float* G     = parts + (size_t)NC * 512 * 576;              // 512*512
  float* c0    = G + 512 * 512;                               // 512*64
  float* c1    = c0 + 512 * 64;
  float* c2    = c1 + 512 * 64;
  u16* wt_h    = (u16*)(c2 + 512 * 64);                       // 64*512
  u16* wt_l    = wt_h + (size_t)DQ * FD;

  init_kernel<<<NPAD / 64, 256, 0, stream>>>(user_emb, item_emb, out, egoT_h, egoT_l);
  gram_kernel<<<dim3(14, NC), 256, 0, stream>>>(v, egoT_h, egoT_l, parts);
  finalize_kernel<<<(512 * 576) / 256, 256, 0, stream>>>(parts, G, c0);
  apply_g_kernel<<<512, 256, 0, stream>>>(G, filters, c0, c1);
  apply_g_kernel<<<512, 256, 0, stream>>>(G, filters + 512, c1, c2);
  prep_wt_kernel<<<128, 256, 0, stream>>>(filters, c0, c1, c2, wt_h, wt_l);
  expand_kernel<<<NPAD / 128, 256, 0, stream>>>(v, wt_h, wt_l, out);
}